// Round 13
// baseline (314.991 us; speedup 1.0000x reference)
//
#include <hip/hip_runtime.h>
#include <hip/hip_bf16.h>
#include <stdint.h>

#define B 2
#define N 1024
#define DIM 1024
#define HEADS 16
#define HD 64
#define E3 (3*DIM)
#define M (B*N)

typedef __hip_bfloat16 bf16;
typedef __attribute__((ext_vector_type(8))) short short8v;
typedef __attribute__((ext_vector_type(4))) float f32x4;
typedef __attribute__((ext_vector_type(4))) unsigned int u32x4;

__device__ __forceinline__ float scrub(float v) {
    return (v == v && fabsf(v) < 1e30f) ? v : 0.0f;
}
__device__ __forceinline__ float b2f(bf16 x) { return scrub(__bfloat162float(x)); }

template<bool FP32>
__device__ __forceinline__ float ldin(const void* p, int i) {
    if (FP32) return scrub(((const float*)p)[i]);
    else      return scrub(__bfloat162float(((const bf16*)p)[i]));
}

__device__ __forceinline__ bool sniff_fp32(const void* x, int tid, int* sbad) {
    if (tid == 0) *sbad = 0;
    __syncthreads();
    if (tid < 64) {
        const unsigned short* u = (const unsigned short*)x;
        int ex = (u[tid] >> 7) & 0xFF;
        if (ex == 0xFF || ex >= 135 || (ex != 0 && ex <= 118))
            atomicAdd(sbad, 1);
    }
    __syncthreads();
    return *sbad > 4;
}

__device__ __forceinline__ short f2bs(float x) {
    bf16 h = __float2bfloat16(x);
    return __builtin_bit_cast(short, h);
}
__device__ __forceinline__ short8v neg8(short8v x) {   // flip bf16 sign bits
    u32x4 u = __builtin_bit_cast(u32x4, x);
    u ^= 0x80008000u;
    return __builtin_bit_cast(short8v, u);
}
__device__ __forceinline__ f32x4 mfma16(short8v a, short8v b, f32x4 c) {
    return __builtin_amdgcn_mfma_f32_16x16x32_bf16(a, b, c, 0, 0, 0);
}

// async 16B global -> LDS (DMA). LDS dest per wave = uniform base + lane*16
// (staging is linear in t); global source is per-lane (carries the swizzle).
__device__ __forceinline__ void gload16(const bf16* g, bf16* l) {
    __builtin_amdgcn_global_load_lds(
        (const __attribute__((address_space(1))) void*)g,
        (__attribute__((address_space(3))) void*)l, 16, 0, 0);
}

// fp32x8 -> (hi, lo) bf16x8 split
__device__ __forceinline__ void cvt8(bf16* dhi, bf16* dlo, const float* s) {
    float4 a = *(const float4*)s;
    float4 b = *(const float4*)(s + 4);
    float v[8] = {a.x,a.y,a.z,a.w,b.x,b.y,b.z,b.w};
    short8v hi, lo;
    #pragma unroll
    for (int e = 0; e < 8; ++e) {
        float f = scrub(v[e]);
        bf16 h = __float2bfloat16(f);
        hi[e] = __builtin_bit_cast(short, h);
        lo[e] = f2bs(f - __bfloat162float(h));
    }
    *(short8v*)dhi = hi;
    *(short8v*)dlo = lo;
}
// fp32x8 -> hi bf16x8 only
__device__ __forceinline__ void cvt8h(bf16* dhi, const float* s) {
    float4 a = *(const float4*)s;
    float4 b = *(const float4*)(s + 4);
    float v[8] = {a.x,a.y,a.z,a.w,b.x,b.y,b.z,b.w};
    short8v hi;
    #pragma unroll
    for (int e = 0; e < 8; ++e)
        hi[e] = f2bs(scrub(v[e]));
    *(short8v*)dhi = hi;
}

// ================= projection LDS layout, BK=32, 128B physical rows (R10-proven) =================
// Source (row, chunk j in 0..3) lives at physical (p = row>>1,
// c = (((row&1)<<2)|j) ^ (p&7)). Zero bank conflicts measured (R10).
#define PLB 2048   // B plane elems (64 rows x 32)

__device__ __forceinline__ short8v frag_ldp(const bf16* base, int row, int j) {
    int p = row >> 1;
    int c = (((row & 1) << 2) | j) ^ (p & 7);
    return *(const short8v*)(base + p*64 + c*8);
}

// ================= async complex bf16 MFMA GEMM core (R12-proven) =================
// Double-buffered LDS, global_load_lds staging issued one K-step ahead,
// ONE barrier per K-step. ASPLIT: A = hi+lo planes (8 MFMA/pair).
template<bool ASPLIT, int BM, int NI>
__device__ __forceinline__ void cgemm_async(
    const bf16* Arh, const bf16* Aih, const bf16* Arl, const bf16* Ail,
    const bf16* Brh, const bf16* Bih,
    int row0, int col0,
    bf16* sA0, bf16* sA1, bf16* sB0, bf16* sB1,
    f32x4 (*accr)[NI], f32x4 (*accs)[NI], f32x4 (*acci)[NI])
{
    constexpr int PLA = BM*32;
    const int t  = threadIdx.x;
    const int w  = t >> 6, l = t & 63;
    const int lr = l & 15, lg = l >> 4;
    const int wm = (NI == 4) ? w : (w >> 1);
    const int wn = (NI == 4) ? 0 : (w & 1);

    // B staging decode (inverse swizzle on the global source)
    const int pb  = t >> 3;
    const int cpb = (t & 7) ^ (pb & 7);
    const int srb = 2*pb + (cpb >> 2);
    const int sjb = cpb & 3;

    auto stage = [&](int buf, int k0) {
        bf16* dsA = buf ? sA1 : sA0;
        bf16* dsB = buf ? sB1 : sB0;
        #pragma unroll
        for (int u = 0; u < BM/64; ++u) {
            int c   = t + 256*u;
            int pa  = c >> 3;
            int cpa = (c & 7) ^ (pa & 7);
            int sra = 2*pa + (cpa >> 2);
            int sja = cpa & 3;
            size_t aoff = (size_t)(row0 + sra)*DIM + k0 + sja*8;
            gload16(Arh + aoff, dsA + c*8);
            gload16(Aih + aoff, dsA + PLA + c*8);
            if constexpr (ASPLIT) {
                gload16(Arl + aoff, dsA + 2*PLA + c*8);
                gload16(Ail + aoff, dsA + 3*PLA + c*8);
            }
        }
        size_t boff = (size_t)(col0 + srb)*DIM + k0 + sjb*8;
        gload16(Brh + boff, dsB + t*8);
        gload16(Bih + boff, dsB + PLB + t*8);
    };

    stage(0, 0);
    __syncthreads();          // drains vmcnt -> buf0 ready
    int cur = 0;

    for (int k0 = 0; k0 < DIM; k0 += 32) {
        if (k0 + 32 < DIM) stage(cur ^ 1, k0 + 32);   // async prefetch next tile

        const bf16* sA = cur ? sA1 : sA0;
        const bf16* sB = cur ? sB1 : sB0;

        short8v arh[2], aih[2], arl[2], ail[2];
        #pragma unroll
        for (int mi = 0; mi < 2; ++mi) {
            int arow = wm*32 + mi*16 + lr;
            arh[mi] = frag_ldp(sA,       arow, lg);
            aih[mi] = frag_ldp(sA + PLA, arow, lg);
            if constexpr (ASPLIT) {
                arl[mi] = frag_ldp(sA + 2*PLA, arow, lg);
                ail[mi] = frag_ldp(sA + 3*PLA, arow, lg);
            }
        }
        #pragma unroll
        for (int ni = 0; ni < NI; ++ni) {
            int brow = wn*32 + ni*16 + lr;
            short8v brh = frag_ldp(sB,       brow, lg);
            short8v bih = frag_ldp(sB + PLB, brow, lg);
            #pragma unroll
            for (int mi = 0; mi < 2; ++mi) {
                accr[mi][ni] = mfma16(arh[mi], brh, accr[mi][ni]);
                accs[mi][ni] = mfma16(aih[mi], bih, accs[mi][ni]);
                acci[mi][ni] = mfma16(arh[mi], bih, acci[mi][ni]);
                acci[mi][ni] = mfma16(aih[mi], brh, acci[mi][ni]);
                if constexpr (ASPLIT) {   // lo * hi
                    accr[mi][ni] = mfma16(arl[mi], brh, accr[mi][ni]);
                    accs[mi][ni] = mfma16(ail[mi], bih, accs[mi][ni]);
                    acci[mi][ni] = mfma16(arl[mi], bih, acci[mi][ni]);
                    acci[mi][ni] = mfma16(ail[mi], brh, acci[mi][ni]);
                }
            }
        }
        __syncthreads();      // all reads of buf[cur] done; prefetch landed
        cur ^= 1;
    }
}

// ================= sync core (fp32 inline-convert fallback only) =================
template<int AMODE, int BMODE, int BM, int NI>
__device__ __forceinline__ void cgemm_sync(
    const void* Aor, const void* Aoi,
    const void* Bor, const void* Boi,
    int row0, int col0,
    bf16* sA, bf16* sB,
    f32x4 (*accr)[NI], f32x4 (*accs)[NI], f32x4 (*acci)[NI])
{
    constexpr int PLA = BM*32;
    const int t  = threadIdx.x;
    const int w  = t >> 6, l = t & 63;
    const int lr = l & 15, lg = l >> 4;
    const int wm = (NI == 4) ? w : (w >> 1);
    const int wn = (NI == 4) ? 0 : (w & 1);

    const int pb  = t >> 3;
    const int cpb = (t & 7) ^ (pb & 7);
    const int srb = 2*pb + (cpb >> 2);
    const int sjb = cpb & 3;

    for (int k0 = 0; k0 < DIM; k0 += 32) {
        #pragma unroll
        for (int u = 0; u < BM/64; ++u) {
            int c   = t + 256*u;
            int pa  = c >> 3;
            int cpa = (c & 7) ^ (pa & 7);
            int sra = 2*pa + (cpa >> 2);
            int sja = cpa & 3;
            size_t aoff = (size_t)(row0 + sra)*DIM + k0 + sja*8;
            bf16* dA = sA + c*8;
            if constexpr (AMODE == 0) {
                *(short8v*)(dA)       = *(const short8v*)((const bf16*)Aor + aoff);
                *(short8v*)(dA + PLA) = *(const short8v*)((const bf16*)Aoi + aoff);
            } else {
                cvt8(dA,       dA + 2*PLA, (const float*)Aor + aoff);
                cvt8(dA + PLA, dA + 3*PLA, (const float*)Aoi + aoff);
            }
        }
        {
            size_t boff = (size_t)(col0 + srb)*DIM + k0 + sjb*8;
            bf16* dB = sB + t*8;
            if constexpr (BMODE == 0) {
                *(short8v*)(dB)       = *(const short8v*)((const bf16*)Bor + boff);
                *(short8v*)(dB + PLB) = *(const short8v*)((const bf16*)Boi + boff);
            } else {
                cvt8(dB,       dB + 2*PLB, (const float*)Bor + boff);
                cvt8(dB + PLB, dB + 3*PLB, (const float*)Boi + boff);
            }
        }
        __syncthreads();

        short8v arh[2], aih[2], arl[2], ail[2];
        #pragma unroll
        for (int mi = 0; mi < 2; ++mi) {
            int arow = wm*32 + mi*16 + lr;
            arh[mi] = frag_ldp(sA,       arow, lg);
            aih[mi] = frag_ldp(sA + PLA, arow, lg);
            if constexpr (AMODE == 2) {
                arl[mi] = frag_ldp(sA + 2*PLA, arow, lg);
                ail[mi] = frag_ldp(sA + 3*PLA, arow, lg);
            }
        }
        #pragma unroll
        for (int ni = 0; ni < NI; ++ni) {
            int brow = wn*32 + ni*16 + lr;
            short8v brh = frag_ldp(sB,       brow, lg);
            short8v bih = frag_ldp(sB + PLB, brow, lg);
            short8v brl, bil;
            if constexpr (BMODE == 2) {
                brl = frag_ldp(sB + 2*PLB, brow, lg);
                bil = frag_ldp(sB + 3*PLB, brow, lg);
            }
            #pragma unroll
            for (int mi = 0; mi < 2; ++mi) {
                accr[mi][ni] = mfma16(arh[mi], brh, accr[mi][ni]);
                accs[mi][ni] = mfma16(aih[mi], bih, accs[mi][ni]);
                acci[mi][ni] = mfma16(arh[mi], bih, acci[mi][ni]);
                acci[mi][ni] = mfma16(aih[mi], brh, acci[mi][ni]);
                if constexpr (BMODE == 2) {
                    accr[mi][ni] = mfma16(arh[mi], brl, accr[mi][ni]);
                    accs[mi][ni] = mfma16(aih[mi], bil, accs[mi][ni]);
                    acci[mi][ni] = mfma16(arh[mi], bil, acci[mi][ni]);
                    acci[mi][ni] = mfma16(aih[mi], brl, acci[mi][ni]);
                }
                if constexpr (AMODE == 2) {
                    accr[mi][ni] = mfma16(arl[mi], brh, accr[mi][ni]);
                    accs[mi][ni] = mfma16(ail[mi], bih, accs[mi][ni]);
                    acci[mi][ni] = mfma16(arl[mi], bih, acci[mi][ni]);
                    acci[mi][ni] = mfma16(ail[mi], brh, acci[mi][ni]);
                }
            }
        }
        __syncthreads();
    }
}

// ================= prepass: fp32 -> bf16 planes (hi/lo, or hi-only) =================
struct PrepArgs {
    const void* src[6];
    bf16* hi[6];
    bf16* lo[6];    // nullptr => hi-only
    int n8[6];
};

__global__ __launch_bounds__(256) void prepass_kernel(PrepArgs a) {
    __shared__ int sbad;
    const int y = blockIdx.y;
    bool f32 = sniff_fp32(a.src[y], threadIdx.x, &sbad);
    if (!f32) return;   // bf16 inputs: planes unused downstream
    const int n8 = a.n8[y];
    bf16* lo = a.lo[y];
    for (int i = blockIdx.x*blockDim.x + threadIdx.x; i < n8; i += gridDim.x*blockDim.x) {
        if (lo) cvt8 (a.hi[y] + (size_t)i*8, lo + (size_t)i*8, (const float*)a.src[y] + (size_t)i*8);
        else    cvt8h(a.hi[y] + (size_t)i*8,                   (const float*)a.src[y] + (size_t)i*8);
    }
}

// ================= Kernel 1: complex QKV projection (tile 64x64, async dbuf — R12 verbatim) =================
template<bool FP32>
__device__ __forceinline__ void qkv_epi(
    const void* fr_, const void* fi_, const void* bqr, const void* bqi,
    bf16* qr, bf16* qi, bf16* kr, bf16* ki, bf16* vr, bf16* vi,
    int row0, int col0,
    f32x4 (*accr)[2], f32x4 (*accs)[2], f32x4 (*acci)[2])
{
    const int t  = threadIdx.x;
    const int w  = t >> 6, l = t & 63;
    const int lr = l & 15, lg = l >> 4;
    const int wm = w >> 1, wn = w & 1;

    #pragma unroll
    for (int ni = 0; ni < 2; ++ni) {
        int col = col0 + wn*32 + ni*16 + lr;
        float bre = ldin<FP32>(bqr, col);
        float bim = ldin<FP32>(bqi, col);
        int s = col % 3;
        int tc = col / 3;
        int h = tc / HD, d = tc % HD;
        #pragma unroll
        for (int mi = 0; mi < 2; ++mi)
        #pragma unroll
        for (int r = 0; r < 4; ++r) {
            int row = row0 + wm*32 + mi*16 + 4*lg + r;
            int bb = row / N, n = row % N;
            float cr = accr[mi][ni][r] - accs[mi][ni][r] + bre;
            float ci = acci[mi][ni][r] + bim;
            if (s == 2) {
                int idxT = ((bb*HEADS + h)*HD + d)*N + n;   // V transposed [b,h,d,n]
                vr[idxT] = __float2bfloat16(scrub(cr));
                vi[idxT] = __float2bfloat16(scrub(ci));
            } else {
                float fre = ldin<FP32>(fr_, n*HD + d);
                float fim = ldin<FP32>(fi_, n*HD + d);
                float rr = cr*fre - ci*fim;
                float ri = cr*fim + ci*fre;
                int idx = ((bb*HEADS + h)*N + n)*HD + d;
                if (s == 0) { qr[idx] = __float2bfloat16(scrub(rr)); qi[idx] = __float2bfloat16(scrub(ri)); }
                else        { kr[idx] = __float2bfloat16(scrub(rr)); ki[idx] = __float2bfloat16(scrub(ri)); }
            }
        }
    }
}

template<int FM>   // 1 = planes (x split, W hi-only), 2 = inline fp32 (ws fallback)
__global__ __launch_bounds__(256, 3) void qkv_kernel(
    const void* xr, const void* xi, const void* fr_, const void* fi_,
    const void* Wr, const void* Wi, const void* bqr, const void* bqi,
    const bf16* xrh, const bf16* xih, const bf16* xrl, const bf16* xil,
    const bf16* wrh, const bf16* wih,
    bf16* qr, bf16* qi, bf16* kr, bf16* ki, bf16* vr, bf16* vi)
{
    __shared__ __align__(16) bf16 sA[2][4*64*32];   // 2 x 16 KB
    __shared__ __align__(16) bf16 sB[2][2*PLB];     // 2 x 8 KB
    __shared__ int sbad;
    bool f32 = sniff_fp32(xr, threadIdx.x, &sbad);

    int wg   = blockIdx.x;
    int xcd  = wg & 7;
    int idx  = wg >> 3;          // 0..191
    int rtin = idx & 1;
    int tmp  = idx >> 1;         // 0..95
    int ctl  = tmp % 6;
    int rtg  = tmp / 6;          // 0..15
    int row0 = (rtg*2 + rtin) * 64;
    int col0 = (xcd*6 + ctl) * 64;

    f32x4 accr[2][2] = {}, accs[2][2] = {}, acci[2][2] = {};
    if (f32) {
        if constexpr (FM == 1)
            cgemm_async<true, 64, 2>(xrh, xih, xrl, xil, wrh, wih,
                                     row0, col0, sA[0], sA[1], sB[0], sB[1],
                                     accr, accs, acci);
        else
            cgemm_sync<2, 2, 64, 2>(xr, xi, Wr, Wi,
                                    row0, col0, sA[0], sB[0],
                                    accr, accs, acci);
        qkv_epi<true >(fr_, fi_, bqr, bqi, qr,qi,kr,ki,vr,vi, row0, col0, accr, accs, acci);
    } else {
        cgemm_async<false, 64, 2>((const bf16*)xr, (const bf16*)xi, nullptr, nullptr,
                                  (const bf16*)Wr, (const bf16*)Wi,
                                  row0, col0, sA[0], sA[1], sB[0], sB[1],
                                  accr, accs, acci);
        qkv_epi<false>(fr_, fi_, bqr, bqi, qr,qi,kr,ki,vr,vi, row0, col0, accr, accs, acci);
    }
}

// ================= Kernel 2: flash-style MFMA attention + T14 async-STAGE split =================
__device__ __forceinline__ short8v frag_ld(const bf16* base, int row, int j) {
    return *(const short8v*)(base + row*64 + ((j ^ (row & 7)) << 3));
}

__global__ __launch_bounds__(256) void attn_kernel(
    const bf16* qr, const bf16* qi, const bf16* kr, const bf16* ki,
    const bf16* vtr, const bf16* vti, bf16* aor_, bf16* aoi_)
{
    __shared__ __align__(16) bf16 skr[64*64];
    __shared__ __align__(16) bf16 ski[64*64];
    __shared__ __align__(16) bf16 svr[64*64];   // Vt tile: [d][m]
    __shared__ __align__(16) bf16 svi[64*64];
    __shared__ __align__(16) bf16 sp[4][16*64]; // per-wave P tile

    const int t  = threadIdx.x;
    const int w  = t >> 6;
    const int l  = t & 63;
    const int lr = l & 15;
    const int lg = l >> 4;
    int wg = blockIdx.x;
    int sw = (wg & 7) * ((int)gridDim.x >> 3) + (wg >> 3);
    const int qt = sw & 15;
    const int bh = sw >> 4;

    const size_t hbase = (size_t)bh * N * HD;

    const bf16* qrg = qr + hbase + (size_t)(qt*64 + w*16 + lr) * HD;
    const bf16* qig = qi + hbase + (size_t)(qt*64 + w*16 + lr) * HD;
    short8v qfr[2], qfi[2], qfrn[2];
    #pragma unroll
    for (int ks = 0; ks < 2; ++ks) {
        qfr[ks] = *(const short8v*)(qrg + 32*ks + 8*lg);
        qfi[ks] = *(const short8v*)(qig + 32*ks + 8*lg);
        qfrn[ks] = neg8(qfr[ks]);
    }

    const int cA = t, cB = t + 256;
    const int rA = cA >> 3, jA = (cA & 7) ^ (rA & 7);
    const int rB = cB >> 3, jB = (cB & 7) ^ (rB & 7);
    const bf16* krg = kr  + hbase;
    const bf16* kig = ki  + hbase;
    const bf16* vrg = vtr + hbase;
    const bf16* vig = vti + hbase;

    f32x4 outr[4], outi[4];
    #pragma unroll
    for (int dt = 0; dt < 4; ++dt) {
        outr[dt] = (f32x4){0.f,0.f,0.f,0.f};
        outi[dt] = (f32x4){0.f,0.f,0.f,0.f};
    }
    float mrow[4] = {-1e30f,-1e30f,-1e30f,-1e30f};
    float lrow[4] = {0.f,0.f,0.f,0.f};

    // T14 async-STAGE split: prefetch K/V tile kt into regs during compute of
    // kt-1; ds_write at top of iteration kt. 8x short8v = +32 VGPR, LDS flat.
    short8v pf0, pf1, pf2, pf3, pf4, pf5, pf6, pf7;
    auto issue = [&](int m0) {
        pf0 = *(const short8v*)(krg + (size_t)(m0+rA)*HD + jA*8);
        pf1 = *(const short8v*)(krg + (size_t)(m0+rB)*HD + jB*8);
        pf2 = *(const short8v*)(kig + (size_t)(m0+rA)*HD + jA*8);
        pf3 = *(const short8v*)(kig + (size_t)(m0+rB)*HD + jB*8);
        pf4 = *(const short8v*)(vrg + (size_t)rA*N + m0 + jA*8);
        pf5 = *(const short8v*)(vrg + (size_t)rB*N + m0 + jB*8);
        pf6 = *(const short8v*)(vig + (size_t)rA*N + m0 + jA*8);
        pf7 = *(const short8v*)(vig + (size_t)rB*N + m0 + jB*8);
    };
    issue(0);

    for (int kt = 0; kt < N/64; ++kt) {
        // write the prefetched tile (reads of the previous tile finished at the
        // closing barrier of the prior iteration -> single-buffer safe)
        *(short8v*)(skr + cA*8) = pf0;
        *(short8v*)(skr + cB*8) = pf1;
        *(short8v*)(ski + cA*8) = pf2;
        *(short8v*)(ski + cB*8) = pf3;
        *(short8v*)(svr + cA*8) = pf4;
        *(short8v*)(svr + cB*8) = pf5;
        *(short8v*)(svi + cA*8) = pf6;
        *(short8v*)(svi + cB*8) = pf7;
        __syncthreads();
        if (kt + 1 < N/64) issue((kt + 1) * 64);   // HBM/L2 latency hides under compute

        f32x4 sr[4], si[4];
        #pragma unroll
        for (int ct = 0; ct < 4; ++ct) {
            f32x4 ar = (f32x4){0.f,0.f,0.f,0.f};
            f32x4 ai = (f32x4){0.f,0.f,0.f,0.f};
            #pragma unroll
            for (int ks = 0; ks < 2; ++ks) {
                short8v kfr = frag_ld(skr, 16*ct + lr, 4*ks + lg);
                short8v kfi = frag_ld(ski, 16*ct + lr, 4*ks + lg);
                ar = mfma16(qfr[ks],  kfr, ar);
                ar = mfma16(qfi[ks],  kfi, ar);
                ai = mfma16(qfi[ks],  kfr, ai);
                ai = mfma16(qfrn[ks], kfi, ai);
            }
            sr[ct] = ar; si[ct] = ai;
        }

        float p[4][4];
        float pmax[4] = {-1e30f,-1e30f,-1e30f,-1e30f};
        #pragma unroll
        for (int ct = 0; ct < 4; ++ct)
        #pragma unroll
        for (int r = 0; r < 4; ++r) {
            float s = sqrtf(sr[ct][r]*sr[ct][r] + si[ct][r]*si[ct][r]) * 0.125f;
            p[ct][r] = s;
            pmax[r] = fmaxf(pmax[r], s);
        }
        #pragma unroll
        for (int mk = 1; mk <= 8; mk <<= 1)
        #pragma unroll
        for (int r = 0; r < 4; ++r)
            pmax[r] = fmaxf(pmax[r], __shfl_xor(pmax[r], mk));

        float fsc[4];
        #pragma unroll
        for (int r = 0; r < 4; ++r) {
            float mnew = fmaxf(mrow[r], pmax[r]);
            fsc[r] = __expf(mrow[r] - mnew);
            mrow[r] = mnew;
        }
        float rsum[4] = {0.f,0.f,0.f,0.f};
        #pragma unroll
        for (int ct = 0; ct < 4; ++ct)
        #pragma unroll
        for (int r = 0; r < 4; ++r) {
            float e = __expf(p[ct][r] - mrow[r]);
            p[ct][r] = e;
            rsum[r] += e;
        }
        #pragma unroll
        for (int mk = 1; mk <= 8; mk <<= 1)
        #pragma unroll
        for (int r = 0; r < 4; ++r)
            rsum[r] += __shfl_xor(rsum[r], mk);
        #pragma unroll
        for (int r = 0; r < 4; ++r)
            lrow[r] = lrow[r]*fsc[r] + rsum[r];
        #pragma unroll
        for (int dt = 0; dt < 4; ++dt)
        #pragma unroll
        for (int r = 0; r < 4; ++r) {
            outr[dt][r] *= fsc[r];
            outi[dt][r] *= fsc[r];
        }

        bf16* pw = sp[w];
        #pragma unroll
        for (int ct = 0; ct < 4; ++ct)
        #pragma unroll
        for (int r = 0; r < 4; ++r) {
            int prow = 4*lg + r;
            int pcol = 16*ct + lr;
            int jj = (pcol >> 3) ^ (prow & 7);
            pw[prow*64 + jj*8 + (pcol & 7)] = __float2bfloat16(p[ct][r]);
        }
        short8v pa[2];
        #pragma unroll
        for (int ks2 = 0; ks2 < 2; ++ks2)
            pa[ks2] = frag_ld(pw, lr, 4*ks2 + lg);

        #pragma unroll
        for (int dt = 0; dt < 4; ++dt)
        #pragma unroll
        for (int ks2 = 0; ks2 < 2; ++ks2) {
            short8v vfr = frag_ld(svr, 16*dt + lr, 4*ks2 + lg);
            short8v vfi = frag_ld(svi, 16*dt + lr, 4*ks2 + lg);
            outr[dt] = mfma16(pa[ks2], vfr, outr[dt]);
            outi[dt] = mfma16(pa[ks2], vfi, outi[dt]);
        }
        __syncthreads();
    }

    const int b_ = bh / HEADS, h_ = bh % HEADS;
    float invl[4];
    #pragma unroll
    for (int r = 0; r < 4; ++r) invl[r] = 1.0f / lrow[r];
    #pragma unroll
    for (int dt = 0; dt < 4; ++dt)
    #pragma unroll
    for (int r = 0; r < 4; ++r) {
        int n_ = qt*64 + w*16 + 4*lg + r;
        int d_ = 16*dt + lr;
        size_t oidx = ((size_t)(b_*N + n_))*DIM + h_*HD + d_;
        aor_[oidx] = __float2bfloat16(scrub(outr[dt][r]*invl[r]));
        aoi_[oidx] = __float2bfloat16(scrub(outi[dt][r]*invl[r]));
    }
}

// ================= Kernel 3: complex out projection (BM=64, NI=2, async dbuf — R12 verbatim) =================
template<int FM>   // 3 = single hi plane, 2 = inline fp32 split (ws fallback)
__global__ __launch_bounds__(256, 4) void outproj_kernel(
    const void* xprobe,
    const bf16* ar, const bf16* ai,
    const void* Wr, const void* Wi, const void* bor, const void* boi,
    const bf16* wrh, const bf16* wih,
    void* out)
{
    __shared__ __align__(16) bf16 sA[2][2*PLB];   // 16 KB
    __shared__ __align__(16) bf16 sB[2][2*PLB];   // 16 KB
    __shared__ int sbad;
    bool f32 = sniff_fp32(xprobe, threadIdx.x, &sbad);

    int wg   = blockIdx.x;
    int xcd  = wg & 7;
    int idx  = wg >> 3;          // 0..63
    int rtin = idx & 1;
    int tmp  = idx >> 1;         // 0..31
    int ctl  = tmp & 1;
    int rtg  = tmp >> 1;         // 0..15
    int row0 = (rtg*2 + rtin) * 64;
    int col0 = (xcd*2 + ctl) * 64;

    const int t  = threadIdx.x;
    const int w  = t >> 6, l = t & 63;
    const int lr = l & 15, lg = l >> 4;
    const int wm = w >> 1, wn = w & 1;

    f32x4 accr[2][2] = {}, accs[2][2] = {}, acci[2][2] = {};
    if (f32) {
        if constexpr (FM == 3)
            cgemm_async<false, 64, 2>(ar, ai, nullptr, nullptr, wrh, wih,
                                      row0, col0, sA[0], sA[1], sB[0], sB[1],
                                      accr, accs, acci);
        else
            cgemm_sync<0, 2, 64, 2>(ar, ai, Wr, Wi,
                                    row0, col0, sA[0], sB[0],
                                    accr, accs, acci);
    } else {
        cgemm_async<false, 64, 2>(ar, ai, nullptr, nullptr,
                                  (const bf16*)Wr, (const bf16*)Wi,
                                  row0, col0, sA[0], sA[1], sB[0], sB[1],
                                  accr, accs, acci);
    }

    #pragma unroll
    for (int ni = 0; ni < 2; ++ni) {
        int col = col0 + wn*32 + ni*16 + lr;
        float bre = f32 ? ldin<true>(bor, col) : ldin<false>(bor, col);
        float bim = f32 ? ldin<true>(boi, col) : ldin<false>(boi, col);
        #pragma unroll
        for (int mi = 0; mi < 2; ++mi)
        #pragma unroll
        for (int r = 0; r < 4; ++r) {
            int row = row0 + wm*32 + mi*16 + 4*lg + r;
            float cr = scrub(accr[mi][ni][r] - accs[mi][ni][r] + bre);
            float ci = scrub(acci[mi][ni][r] + bim);
            if (f32) {
                ((float*)out)[(size_t)row*DIM + col]                 = cr;
                ((float*)out)[(size_t)M*DIM + (size_t)row*DIM + col] = ci;
            } else {
                ((bf16*)out)[(size_t)row*DIM + col]                  = __float2bfloat16(cr);
                ((bf16*)out)[(size_t)M*DIM + (size_t)row*DIM + col]  = __float2bfloat16(ci);
            }
        }
    }
}

// ================= host =================
extern "C" void kernel_launch(void* const* d_in, const int* in_sizes, int n_in,
                              void* d_out, int out_size, void* d_ws, size_t ws_size,
                              hipStream_t stream)
{
    const void* xr     = d_in[0];
    const void* xi     = d_in[1];
    const void* fr     = d_in[2];
    const void* fi     = d_in[3];
    const void* Wqkv_r = d_in[4];
    const void* Wqkv_i = d_in[5];
    const void* bqkv_r = d_in[6];
    const void* bqkv_i = d_in[7];
    const void* Wout_r = d_in[8];
    const void* Wout_i = d_in[9];
    const void* bout_r = d_in[10];
    const void* bout_i = d_in[11];

    bf16* w = (bf16*)d_ws;
    const size_t QS  = (size_t)B*HEADS*N*HD;   // 2,097,152
    const size_t XS  = (size_t)M*DIM;          // 2,097,152
    const size_t WQS = (size_t)E3*DIM;         // 3,145,728
    const size_t WOS = (size_t)DIM*DIM;        // 1,048,576

    bf16* qr   = w;          bf16* qi   = qr  + QS;
    bf16* kr   = qi  + QS;   bf16* ki   = kr  + QS;
    bf16* vr   = ki  + QS;   bf16* vi   = vr  + QS;   // TRANSPOSED [b,h,d,n]
    bf16* aor_ = vi  + QS;   bf16* aoi_ = aor_ + QS;
    bf16* xrh = aoi_ + QS;   bf16* xih = xrh + XS;
    bf16* xrl = xih + XS;    bf16* xil = xrl + XS;
    bf16* wqrh = xil + XS;   bf16* wqih = wqrh + WQS;
    bf16* worh = wqih + WQS; bf16* woih = worh + WOS;

    const size_t need = (size_t)(8*QS + 4*XS + 2*WQS + 2*WOS) * sizeof(bf16);
    const bool pre = ws_size >= need;

    if (pre) {
        PrepArgs a;
        a.src[0] = xr;     a.hi[0] = xrh;  a.lo[0] = xrl;    a.n8[0] = (int)(XS/8);
        a.src[1] = xi;     a.hi[1] = xih;  a.lo[1] = xil;    a.n8[1] = (int)(XS/8);
        a.src[2] = Wqkv_r; a.hi[2] = wqrh; a.lo[2] = nullptr; a.n8[2] = (int)(WQS/8);
        a.src[3] = Wqkv_i; a.hi[3] = wqih; a.lo[3] = nullptr; a.n8[3] = (int)(WQS/8);
        a.src[4] = Wout_r; a.hi[4] = worh; a.lo[4] = nullptr; a.n8[4] = (int)(WOS/8);
        a.src[5] = Wout_i; a.hi[5] = woih; a.lo[5] = nullptr; a.n8[5] = (int)(WOS/8);
        prepass_kernel<<<dim3(1536, 6), dim3(256), 0, stream>>>(a);

        qkv_kernel<1><<<dim3((E3/64)*(M/64)), dim3(256), 0, stream>>>(
            xr, xi, fr, fi, Wqkv_r, Wqkv_i, bqkv_r, bqkv_i,
            xrh, xih, xrl, xil, wqrh, wqih,
            qr, qi, kr, ki, vr, vi);
    } else {
        qkv_kernel<2><<<dim3((E3/64)*(M/64)), dim3(256), 0, stream>>>(
            xr, xi, fr, fi, Wqkv_r, Wqkv_i, bqkv_r, bqkv_i,
            nullptr, nullptr, nullptr, nullptr, nullptr, nullptr,
            qr, qi, kr, ki, vr, vi);
    }

    attn_kernel<<<dim3(B*HEADS*(N/64)), dim3(256), 0, stream>>>(
        qr, qi, kr, ki, vr, vi, aor_, aoi_);

    if (pre) {
        outproj_kernel<3><<<dim3((DIM/64)*(M/64)), dim3(256), 0, stream>>>(
            xr, aor_, aoi_, Wout_r, Wout_i, bout_r, bout_i,
            worh, woih, d_out);
    } else {
        outproj_kernel<2><<<dim3((DIM/64)*(M/64)), dim3(256), 0, stream>>>(
            xr, aor_, aoi_, Wout_r, Wout_i, bout_r, bout_i,
            nullptr, nullptr, d_out);
    }
}

// Round 14
// 299.464 us; speedup vs baseline: 1.0518x; 1.0518x over previous
//
#include <hip/hip_runtime.h>
#include <hip/hip_bf16.h>
#include <stdint.h>

#define B 2
#define N 1024
#define DIM 1024
#define HEADS 16
#define HD 64
#define E3 (3*DIM)
#define M (B*N)

typedef __hip_bfloat16 bf16;
typedef __attribute__((ext_vector_type(8))) short short8v;
typedef __attribute__((ext_vector_type(4))) float f32x4;
typedef __attribute__((ext_vector_type(4))) unsigned int u32x4;

__device__ __forceinline__ float scrub(float v) {
    return (v == v && fabsf(v) < 1e30f) ? v : 0.0f;
}
__device__ __forceinline__ float b2f(bf16 x) { return scrub(__bfloat162float(x)); }

template<bool FP32>
__device__ __forceinline__ float ldin(const void* p, int i) {
    if (FP32) return scrub(((const float*)p)[i]);
    else      return scrub(__bfloat162float(((const bf16*)p)[i]));
}

__device__ __forceinline__ bool sniff_fp32(const void* x, int tid, int* sbad) {
    if (tid == 0) *sbad = 0;
    __syncthreads();
    if (tid < 64) {
        const unsigned short* u = (const unsigned short*)x;
        int ex = (u[tid] >> 7) & 0xFF;
        if (ex == 0xFF || ex >= 135 || (ex != 0 && ex <= 118))
            atomicAdd(sbad, 1);
    }
    __syncthreads();
    return *sbad > 4;
}

__device__ __forceinline__ short f2bs(float x) {
    bf16 h = __float2bfloat16(x);
    return __builtin_bit_cast(short, h);
}
__device__ __forceinline__ short8v neg8(short8v x) {   // flip bf16 sign bits
    u32x4 u = __builtin_bit_cast(u32x4, x);
    u ^= 0x80008000u;
    return __builtin_bit_cast(short8v, u);
}
__device__ __forceinline__ f32x4 mfma16(short8v a, short8v b, f32x4 c) {
    return __builtin_amdgcn_mfma_f32_16x16x32_bf16(a, b, c, 0, 0, 0);
}

// async 16B global -> LDS (DMA). LDS dest per wave = uniform base + lane*16
// (staging is linear in t); global source is per-lane (carries the swizzle).
__device__ __forceinline__ void gload16(const bf16* g, bf16* l) {
    __builtin_amdgcn_global_load_lds(
        (const __attribute__((address_space(1))) void*)g,
        (__attribute__((address_space(3))) void*)l, 16, 0, 0);
}

// fp32x8 -> (hi, lo) bf16x8 split
__device__ __forceinline__ void cvt8(bf16* dhi, bf16* dlo, const float* s) {
    float4 a = *(const float4*)s;
    float4 b = *(const float4*)(s + 4);
    float v[8] = {a.x,a.y,a.z,a.w,b.x,b.y,b.z,b.w};
    short8v hi, lo;
    #pragma unroll
    for (int e = 0; e < 8; ++e) {
        float f = scrub(v[e]);
        bf16 h = __float2bfloat16(f);
        hi[e] = __builtin_bit_cast(short, h);
        lo[e] = f2bs(f - __bfloat162float(h));
    }
    *(short8v*)dhi = hi;
    *(short8v*)dlo = lo;
}
// fp32x8 -> hi bf16x8 only
__device__ __forceinline__ void cvt8h(bf16* dhi, const float* s) {
    float4 a = *(const float4*)s;
    float4 b = *(const float4*)(s + 4);
    float v[8] = {a.x,a.y,a.z,a.w,b.x,b.y,b.z,b.w};
    short8v hi;
    #pragma unroll
    for (int e = 0; e < 8; ++e)
        hi[e] = f2bs(scrub(v[e]));
    *(short8v*)dhi = hi;
}

// ================= projection LDS layout, BK=32, 128B physical rows (R10-proven) =================
#define PLB 2048   // B plane elems (64 rows x 32)

__device__ __forceinline__ short8v frag_ldp(const bf16* base, int row, int j) {
    int p = row >> 1;
    int c = (((row & 1) << 2) | j) ^ (p & 7);
    return *(const short8v*)(base + p*64 + c*8);
}

// ================= async complex bf16 MFMA GEMM core (R12-proven) =================
template<bool ASPLIT, int BM, int NI>
__device__ __forceinline__ void cgemm_async(
    const bf16* Arh, const bf16* Aih, const bf16* Arl, const bf16* Ail,
    const bf16* Brh, const bf16* Bih,
    int row0, int col0,
    bf16* sA0, bf16* sA1, bf16* sB0, bf16* sB1,
    f32x4 (*accr)[NI], f32x4 (*accs)[NI], f32x4 (*acci)[NI])
{
    constexpr int PLA = BM*32;
    const int t  = threadIdx.x;
    const int w  = t >> 6, l = t & 63;
    const int lr = l & 15, lg = l >> 4;
    const int wm = (NI == 4) ? w : (w >> 1);
    const int wn = (NI == 4) ? 0 : (w & 1);

    const int pb  = t >> 3;
    const int cpb = (t & 7) ^ (pb & 7);
    const int srb = 2*pb + (cpb >> 2);
    const int sjb = cpb & 3;

    auto stage = [&](int buf, int k0) {
        bf16* dsA = buf ? sA1 : sA0;
        bf16* dsB = buf ? sB1 : sB0;
        #pragma unroll
        for (int u = 0; u < BM/64; ++u) {
            int c   = t + 256*u;
            int pa  = c >> 3;
            int cpa = (c & 7) ^ (pa & 7);
            int sra = 2*pa + (cpa >> 2);
            int sja = cpa & 3;
            size_t aoff = (size_t)(row0 + sra)*DIM + k0 + sja*8;
            gload16(Arh + aoff, dsA + c*8);
            gload16(Aih + aoff, dsA + PLA + c*8);
            if constexpr (ASPLIT) {
                gload16(Arl + aoff, dsA + 2*PLA + c*8);
                gload16(Ail + aoff, dsA + 3*PLA + c*8);
            }
        }
        size_t boff = (size_t)(col0 + srb)*DIM + k0 + sjb*8;
        gload16(Brh + boff, dsB + t*8);
        gload16(Bih + boff, dsB + PLB + t*8);
    };

    stage(0, 0);
    __syncthreads();
    int cur = 0;

    for (int k0 = 0; k0 < DIM; k0 += 32) {
        if (k0 + 32 < DIM) stage(cur ^ 1, k0 + 32);

        const bf16* sA = cur ? sA1 : sA0;
        const bf16* sB = cur ? sB1 : sB0;

        short8v arh[2], aih[2], arl[2], ail[2];
        #pragma unroll
        for (int mi = 0; mi < 2; ++mi) {
            int arow = wm*32 + mi*16 + lr;
            arh[mi] = frag_ldp(sA,       arow, lg);
            aih[mi] = frag_ldp(sA + PLA, arow, lg);
            if constexpr (ASPLIT) {
                arl[mi] = frag_ldp(sA + 2*PLA, arow, lg);
                ail[mi] = frag_ldp(sA + 3*PLA, arow, lg);
            }
        }
        #pragma unroll
        for (int ni = 0; ni < NI; ++ni) {
            int brow = wn*32 + ni*16 + lr;
            short8v brh = frag_ldp(sB,       brow, lg);
            short8v bih = frag_ldp(sB + PLB, brow, lg);
            #pragma unroll
            for (int mi = 0; mi < 2; ++mi) {
                accr[mi][ni] = mfma16(arh[mi], brh, accr[mi][ni]);
                accs[mi][ni] = mfma16(aih[mi], bih, accs[mi][ni]);
                acci[mi][ni] = mfma16(arh[mi], bih, acci[mi][ni]);
                acci[mi][ni] = mfma16(aih[mi], brh, acci[mi][ni]);
                if constexpr (ASPLIT) {
                    accr[mi][ni] = mfma16(arl[mi], brh, accr[mi][ni]);
                    accs[mi][ni] = mfma16(ail[mi], bih, accs[mi][ni]);
                    acci[mi][ni] = mfma16(arl[mi], bih, acci[mi][ni]);
                    acci[mi][ni] = mfma16(ail[mi], brh, acci[mi][ni]);
                }
            }
        }
        __syncthreads();
        cur ^= 1;
    }
}

// ================= sync core (fp32 inline-convert fallback only) =================
template<int AMODE, int BMODE, int BM, int NI>
__device__ __forceinline__ void cgemm_sync(
    const void* Aor, const void* Aoi,
    const void* Bor, const void* Boi,
    int row0, int col0,
    bf16* sA, bf16* sB,
    f32x4 (*accr)[NI], f32x4 (*accs)[NI], f32x4 (*acci)[NI])
{
    constexpr int PLA = BM*32;
    const int t  = threadIdx.x;
    const int w  = t >> 6, l = t & 63;
    const int lr = l & 15, lg = l >> 4;
    const int wm = (NI == 4) ? w : (w >> 1);
    const int wn = (NI == 4) ? 0 : (w & 1);

    const int pb  = t >> 3;
    const int cpb = (t & 7) ^ (pb & 7);
    const int srb = 2*pb + (cpb >> 2);
    const int sjb = cpb & 3;

    for (int k0 = 0; k0 < DIM; k0 += 32) {
        #pragma unroll
        for (int u = 0; u < BM/64; ++u) {
            int c   = t + 256*u;
            int pa  = c >> 3;
            int cpa = (c & 7) ^ (pa & 7);
            int sra = 2*pa + (cpa >> 2);
            int sja = cpa & 3;
            size_t aoff = (size_t)(row0 + sra)*DIM + k0 + sja*8;
            bf16* dA = sA + c*8;
            if constexpr (AMODE == 0) {
                *(short8v*)(dA)       = *(const short8v*)((const bf16*)Aor + aoff);
                *(short8v*)(dA + PLA) = *(const short8v*)((const bf16*)Aoi + aoff);
            } else {
                cvt8(dA,       dA + 2*PLA, (const float*)Aor + aoff);
                cvt8(dA + PLA, dA + 3*PLA, (const float*)Aoi + aoff);
            }
        }
        {
            size_t boff = (size_t)(col0 + srb)*DIM + k0 + sjb*8;
            bf16* dB = sB + t*8;
            if constexpr (BMODE == 0) {
                *(short8v*)(dB)       = *(const short8v*)((const bf16*)Bor + boff);
                *(short8v*)(dB + PLB) = *(const short8v*)((const bf16*)Boi + boff);
            } else {
                cvt8(dB,       dB + 2*PLB, (const float*)Bor + boff);
                cvt8(dB + PLB, dB + 3*PLB, (const float*)Boi + boff);
            }
        }
        __syncthreads();

        short8v arh[2], aih[2], arl[2], ail[2];
        #pragma unroll
        for (int mi = 0; mi < 2; ++mi) {
            int arow = wm*32 + mi*16 + lr;
            arh[mi] = frag_ldp(sA,       arow, lg);
            aih[mi] = frag_ldp(sA + PLA, arow, lg);
            if constexpr (AMODE == 2) {
                arl[mi] = frag_ldp(sA + 2*PLA, arow, lg);
                ail[mi] = frag_ldp(sA + 3*PLA, arow, lg);
            }
        }
        #pragma unroll
        for (int ni = 0; ni < NI; ++ni) {
            int brow = wn*32 + ni*16 + lr;
            short8v brh = frag_ldp(sB,       brow, lg);
            short8v bih = frag_ldp(sB + PLB, brow, lg);
            short8v brl, bil;
            if constexpr (BMODE == 2) {
                brl = frag_ldp(sB + 2*PLB, brow, lg);
                bil = frag_ldp(sB + 3*PLB, brow, lg);
            }
            #pragma unroll
            for (int mi = 0; mi < 2; ++mi) {
                accr[mi][ni] = mfma16(arh[mi], brh, accr[mi][ni]);
                accs[mi][ni] = mfma16(aih[mi], bih, accs[mi][ni]);
                acci[mi][ni] = mfma16(arh[mi], bih, acci[mi][ni]);
                acci[mi][ni] = mfma16(aih[mi], brh, acci[mi][ni]);
                if constexpr (BMODE == 2) {
                    accr[mi][ni] = mfma16(arh[mi], brl, accr[mi][ni]);
                    accs[mi][ni] = mfma16(aih[mi], bil, accs[mi][ni]);
                    acci[mi][ni] = mfma16(arh[mi], bil, acci[mi][ni]);
                    acci[mi][ni] = mfma16(aih[mi], brl, acci[mi][ni]);
                }
                if constexpr (AMODE == 2) {
                    accr[mi][ni] = mfma16(arl[mi], brh, accr[mi][ni]);
                    accs[mi][ni] = mfma16(ail[mi], bih, accs[mi][ni]);
                    acci[mi][ni] = mfma16(arl[mi], bih, acci[mi][ni]);
                    acci[mi][ni] = mfma16(ail[mi], brh, acci[mi][ni]);
                }
            }
        }
        __syncthreads();
    }
}

// ================= prepass: fp32 -> bf16 planes (hi/lo, or hi-only) =================
struct PrepArgs {
    const void* src[6];
    bf16* hi[6];
    bf16* lo[6];    // nullptr => hi-only
    int n8[6];
};

__global__ __launch_bounds__(256) void prepass_kernel(PrepArgs a) {
    __shared__ int sbad;
    const int y = blockIdx.y;
    bool f32 = sniff_fp32(a.src[y], threadIdx.x, &sbad);
    if (!f32) return;
    const int n8 = a.n8[y];
    bf16* lo = a.lo[y];
    for (int i = blockIdx.x*blockDim.x + threadIdx.x; i < n8; i += gridDim.x*blockDim.x) {
        if (lo) cvt8 (a.hi[y] + (size_t)i*8, lo + (size_t)i*8, (const float*)a.src[y] + (size_t)i*8);
        else    cvt8h(a.hi[y] + (size_t)i*8,                   (const float*)a.src[y] + (size_t)i*8);
    }
}

// ================= Kernel 1: complex QKV projection (R12/R13 verbatim) =================
template<bool FP32>
__device__ __forceinline__ void qkv_epi(
    const void* fr_, const void* fi_, const void* bqr, const void* bqi,
    bf16* qr, bf16* qi, bf16* kr, bf16* ki, bf16* vr, bf16* vi,
    int row0, int col0,
    f32x4 (*accr)[2], f32x4 (*accs)[2], f32x4 (*acci)[2])
{
    const int t  = threadIdx.x;
    const int w  = t >> 6, l = t & 63;
    const int lr = l & 15, lg = l >> 4;
    const int wm = w >> 1, wn = w & 1;

    #pragma unroll
    for (int ni = 0; ni < 2; ++ni) {
        int col = col0 + wn*32 + ni*16 + lr;
        float bre = ldin<FP32>(bqr, col);
        float bim = ldin<FP32>(bqi, col);
        int s = col % 3;
        int tc = col / 3;
        int h = tc / HD, d = tc % HD;
        #pragma unroll
        for (int mi = 0; mi < 2; ++mi)
        #pragma unroll
        for (int r = 0; r < 4; ++r) {
            int row = row0 + wm*32 + mi*16 + 4*lg + r;
            int bb = row / N, n = row % N;
            float cr = accr[mi][ni][r] - accs[mi][ni][r] + bre;
            float ci = acci[mi][ni][r] + bim;
            if (s == 2) {
                int idxT = ((bb*HEADS + h)*HD + d)*N + n;   // V transposed [b,h,d,n]
                vr[idxT] = __float2bfloat16(scrub(cr));
                vi[idxT] = __float2bfloat16(scrub(ci));
            } else {
                float fre = ldin<FP32>(fr_, n*HD + d);
                float fim = ldin<FP32>(fi_, n*HD + d);
                float rr = cr*fre - ci*fim;
                float ri = cr*fim + ci*fre;
                int idx = ((bb*HEADS + h)*N + n)*HD + d;
                if (s == 0) { qr[idx] = __float2bfloat16(scrub(rr)); qi[idx] = __float2bfloat16(scrub(ri)); }
                else        { kr[idx] = __float2bfloat16(scrub(rr)); ki[idx] = __float2bfloat16(scrub(ri)); }
            }
        }
    }
}

template<int FM>
__global__ __launch_bounds__(256, 3) void qkv_kernel(
    const void* xr, const void* xi, const void* fr_, const void* fi_,
    const void* Wr, const void* Wi, const void* bqr, const void* bqi,
    const bf16* xrh, const bf16* xih, const bf16* xrl, const bf16* xil,
    const bf16* wrh, const bf16* wih,
    bf16* qr, bf16* qi, bf16* kr, bf16* ki, bf16* vr, bf16* vi)
{
    __shared__ __align__(16) bf16 sA[2][4*64*32];
    __shared__ __align__(16) bf16 sB[2][2*PLB];
    __shared__ int sbad;
    bool f32 = sniff_fp32(xr, threadIdx.x, &sbad);

    int wg   = blockIdx.x;
    int xcd  = wg & 7;
    int idx  = wg >> 3;
    int rtin = idx & 1;
    int tmp  = idx >> 1;
    int ctl  = tmp % 6;
    int rtg  = tmp / 6;
    int row0 = (rtg*2 + rtin) * 64;
    int col0 = (xcd*6 + ctl) * 64;

    f32x4 accr[2][2] = {}, accs[2][2] = {}, acci[2][2] = {};
    if (f32) {
        if constexpr (FM == 1)
            cgemm_async<true, 64, 2>(xrh, xih, xrl, xil, wrh, wih,
                                     row0, col0, sA[0], sA[1], sB[0], sB[1],
                                     accr, accs, acci);
        else
            cgemm_sync<2, 2, 64, 2>(xr, xi, Wr, Wi,
                                    row0, col0, sA[0], sB[0],
                                    accr, accs, acci);
        qkv_epi<true >(fr_, fi_, bqr, bqi, qr,qi,kr,ki,vr,vi, row0, col0, accr, accs, acci);
    } else {
        cgemm_async<false, 64, 2>((const bf16*)xr, (const bf16*)xi, nullptr, nullptr,
                                  (const bf16*)Wr, (const bf16*)Wi,
                                  row0, col0, sA[0], sA[1], sB[0], sB[1],
                                  accr, accs, acci);
        qkv_epi<false>(fr_, fi_, bqr, bqi, qr,qi,kr,ki,vr,vi, row0, col0, accr, accs, acci);
    }
}

// ===== Kernel 2: flash-style MFMA attention — dbuf K/V LDS, ONE barrier/iter =====
__device__ __forceinline__ short8v frag_ld(const bf16* base, int row, int j) {
    return *(const short8v*)(base + row*64 + ((j ^ (row & 7)) << 3));
}

__global__ __launch_bounds__(256) void attn_kernel(
    const bf16* qr, const bf16* qi, const bf16* kr, const bf16* ki,
    const bf16* vtr, const bf16* vti, bf16* aor_, bf16* aoi_)
{
    __shared__ __align__(16) bf16 skr[2][64*64];
    __shared__ __align__(16) bf16 ski[2][64*64];
    __shared__ __align__(16) bf16 svr[2][64*64];   // Vt tile: [d][m]
    __shared__ __align__(16) bf16 svi[2][64*64];
    __shared__ __align__(16) bf16 sp[4][16*64];    // per-wave P tile
    // LDS = 4*16KB + 8KB = 72KB -> 2 blocks/CU (grid is 2/CU anyway: no loss)

    const int t  = threadIdx.x;
    const int w  = t >> 6;
    const int l  = t & 63;
    const int lr = l & 15;
    const int lg = l >> 4;
    int wg = blockIdx.x;
    int sw = (wg & 7) * ((int)gridDim.x >> 3) + (wg >> 3);
    const int qt = sw & 15;
    const int bh = sw >> 4;

    const size_t hbase = (size_t)bh * N * HD;

    const bf16* qrg = qr + hbase + (size_t)(qt*64 + w*16 + lr) * HD;
    const bf16* qig = qi + hbase + (size_t)(qt*64 + w*16 + lr) * HD;
    short8v qfr[2], qfi[2], qfrn[2];
    #pragma unroll
    for (int ks = 0; ks < 2; ++ks) {
        qfr[ks] = *(const short8v*)(qrg + 32*ks + 8*lg);
        qfi[ks] = *(const short8v*)(qig + 32*ks + 8*lg);
        qfrn[ks] = neg8(qfr[ks]);
    }

    const int cA = t, cB = t + 256;
    const int rA = cA >> 3, jA = (cA & 7) ^ (rA & 7);
    const int rB = cB >> 3, jB = (cB & 7) ^ (rB & 7);
    const bf16* krg = kr  + hbase;
    const bf16* kig = ki  + hbase;
    const bf16* vrg = vtr + hbase;
    const bf16* vig = vti + hbase;

    f32x4 outr[4], outi[4];
    #pragma unroll
    for (int dt = 0; dt < 4; ++dt) {
        outr[dt] = (f32x4){0.f,0.f,0.f,0.f};
        outi[dt] = (f32x4){0.f,0.f,0.f,0.f};
    }
    float mrow[4] = {-1e30f,-1e30f,-1e30f,-1e30f};
    float lrow[4] = {0.f,0.f,0.f,0.f};

    // prefetch regs (T14) + double-buffered LDS: write tile k+1 into buf^1
    // AFTER compute of tile k issues; single barrier per iteration.
    short8v pf0, pf1, pf2, pf3, pf4, pf5, pf6, pf7;
    auto issue = [&](int m0) {
        pf0 = *(const short8v*)(krg + (size_t)(m0+rA)*HD + jA*8);
        pf1 = *(const short8v*)(krg + (size_t)(m0+rB)*HD + jB*8);
        pf2 = *(const short8v*)(kig + (size_t)(m0+rA)*HD + jA*8);
        pf3 = *(const short8v*)(kig + (size_t)(m0+rB)*HD + jB*8);
        pf4 = *(const short8v*)(vrg + (size_t)rA*N + m0 + jA*8);
        pf5 = *(const short8v*)(vrg + (size_t)rB*N + m0 + jB*8);
        pf6 = *(const short8v*)(vig + (size_t)rA*N + m0 + jA*8);
        pf7 = *(const short8v*)(vig + (size_t)rB*N + m0 + jB*8);
    };
    auto wrt = [&](int buf) {
        *(short8v*)(skr[buf] + cA*8) = pf0;
        *(short8v*)(skr[buf] + cB*8) = pf1;
        *(short8v*)(ski[buf] + cA*8) = pf2;
        *(short8v*)(ski[buf] + cB*8) = pf3;
        *(short8v*)(svr[buf] + cA*8) = pf4;
        *(short8v*)(svr[buf] + cB*8) = pf5;
        *(short8v*)(svi[buf] + cA*8) = pf6;
        *(short8v*)(svi[buf] + cB*8) = pf7;
    };

    issue(0);
    wrt(0);
    __syncthreads();
    int cur = 0;

    for (int kt = 0; kt < N/64; ++kt) {
        if (kt + 1 < N/64) issue((kt + 1) * 64);   // loads fly during compute

        f32x4 sr[4], si[4];
        #pragma unroll
        for (int ct = 0; ct < 4; ++ct) {
            f32x4 ar = (f32x4){0.f,0.f,0.f,0.f};
            f32x4 ai = (f32x4){0.f,0.f,0.f,0.f};
            #pragma unroll
            for (int ks = 0; ks < 2; ++ks) {
                short8v kfr = frag_ld(skr[cur], 16*ct + lr, 4*ks + lg);
                short8v kfi = frag_ld(ski[cur], 16*ct + lr, 4*ks + lg);
                ar = mfma16(qfr[ks],  kfr, ar);
                ar = mfma16(qfi[ks],  kfi, ar);
                ai = mfma16(qfi[ks],  kfr, ai);
                ai = mfma16(qfrn[ks], kfi, ai);
            }
            sr[ct] = ar; si[ct] = ai;
        }

        float p[4][4];
        float pmax[4] = {-1e30f,-1e30f,-1e30f,-1e30f};
        #pragma unroll
        for (int ct = 0; ct < 4; ++ct)
        #pragma unroll
        for (int r = 0; r < 4; ++r) {
            float s = sqrtf(sr[ct][r]*sr[ct][r] + si[ct][r]*si[ct][r]) * 0.125f;
            p[ct][r] = s;
            pmax[r] = fmaxf(pmax[r], s);
        }
        #pragma unroll
        for (int mk = 1; mk <= 8; mk <<= 1)
        #pragma unroll
        for (int r = 0; r < 4; ++r)
            pmax[r] = fmaxf(pmax[r], __shfl_xor(pmax[r], mk));

        float fsc[4];
        #pragma unroll
        for (int r = 0; r < 4; ++r) {
            float mnew = fmaxf(mrow[r], pmax[r]);
            fsc[r] = __expf(mrow[r] - mnew);
            mrow[r] = mnew;
        }
        float rsum[4] = {0.f,0.f,0.f,0.f};
        #pragma unroll
        for (int ct = 0; ct < 4; ++ct)
        #pragma unroll
        for (int r = 0; r < 4; ++r) {
            float e = __expf(p[ct][r] - mrow[r]);
            p[ct][r] = e;
            rsum[r] += e;
        }
        #pragma unroll
        for (int mk = 1; mk <= 8; mk <<= 1)
        #pragma unroll
        for (int r = 0; r < 4; ++r)
            rsum[r] += __shfl_xor(rsum[r], mk);
        #pragma unroll
        for (int r = 0; r < 4; ++r)
            lrow[r] = lrow[r]*fsc[r] + rsum[r];
        #pragma unroll
        for (int dt = 0; dt < 4; ++dt)
        #pragma unroll
        for (int r = 0; r < 4; ++r) {
            outr[dt][r] *= fsc[r];
            outi[dt][r] *= fsc[r];
        }

        bf16* pw = sp[w];
        #pragma unroll
        for (int ct = 0; ct < 4; ++ct)
        #pragma unroll
        for (int r = 0; r < 4; ++r) {
            int prow = 4*lg + r;
            int pcol = 16*ct + lr;
            int jj = (pcol >> 3) ^ (prow & 7);
            pw[prow*64 + jj*8 + (pcol & 7)] = __float2bfloat16(p[ct][r]);
        }
        short8v pa[2];
        #pragma unroll
        for (int ks2 = 0; ks2 < 2; ++ks2)
            pa[ks2] = frag_ld(pw, lr, 4*ks2 + lg);

        #pragma unroll
        for (int dt = 0; dt < 4; ++dt)
        #pragma unroll
        for (int ks2 = 0; ks2 < 2; ++ks2) {
            short8v vfr = frag_ld(svr[cur], 16*dt + lr, 4*ks2 + lg);
            short8v vfi = frag_ld(svi[cur], 16*dt + lr, 4*ks2 + lg);
            outr[dt] = mfma16(pa[ks2], vfr, outr[dt]);
            outi[dt] = mfma16(pa[ks2], vfi, outi[dt]);
        }

        if (kt + 1 < N/64) wrt(cur ^ 1);   // vmcnt wait drained under compute
        __syncthreads();                   // publish buf[cur^1]; sp reuse safe (per-wave)
        cur ^= 1;
    }

    const int b_ = bh / HEADS, h_ = bh % HEADS;
    float invl[4];
    #pragma unroll
    for (int r = 0; r < 4; ++r) invl[r] = 1.0f / lrow[r];
    #pragma unroll
    for (int dt = 0; dt < 4; ++dt)
    #pragma unroll
    for (int r = 0; r < 4; ++r) {
        int n_ = qt*64 + w*16 + 4*lg + r;
        int d_ = 16*dt + lr;
        size_t oidx = ((size_t)(b_*N + n_))*DIM + h_*HD + d_;
        aor_[oidx] = __float2bfloat16(scrub(outr[dt][r]*invl[r]));
        aoi_[oidx] = __float2bfloat16(scrub(outi[dt][r]*invl[r]));
    }
}

// ================= Kernel 3: complex out projection (R12 verbatim) =================
template<int FM>
__global__ __launch_bounds__(256, 4) void outproj_kernel(
    const void* xprobe,
    const bf16* ar, const bf16* ai,
    const void* Wr, const void* Wi, const void* bor, const void* boi,
    const bf16* wrh, const bf16* wih,
    void* out)
{
    __shared__ __align__(16) bf16 sA[2][2*PLB];
    __shared__ __align__(16) bf16 sB[2][2*PLB];
    __shared__ int sbad;
    bool f32 = sniff_fp32(xprobe, threadIdx.x, &sbad);

    int wg   = blockIdx.x;
    int xcd  = wg & 7;
    int idx  = wg >> 3;
    int rtin = idx & 1;
    int tmp  = idx >> 1;
    int ctl  = tmp & 1;
    int rtg  = tmp >> 1;
    int row0 = (rtg*2 + rtin) * 64;
    int col0 = (xcd*2 + ctl) * 64;

    const int t  = threadIdx.x;
    const int w  = t >> 6, l = t & 63;
    const int lr = l & 15, lg = l >> 4;
    const int wm = w >> 1, wn = w & 1;

    f32x4 accr[2][2] = {}, accs[2][2] = {}, acci[2][2] = {};
    if (f32) {
        if constexpr (FM == 3)
            cgemm_async<false, 64, 2>(ar, ai, nullptr, nullptr, wrh, wih,
                                      row0, col0, sA[0], sA[1], sB[0], sB[1],
                                      accr, accs, acci);
        else
            cgemm_sync<0, 2, 64, 2>(ar, ai, Wr, Wi,
                                    row0, col0, sA[0], sB[0],
                                    accr, accs, acci);
    } else {
        cgemm_async<false, 64, 2>(ar, ai, nullptr, nullptr,
                                  (const bf16*)Wr, (const bf16*)Wi,
                                  row0, col0, sA[0], sA[1], sB[0], sB[1],
                                  accr, accs, acci);
    }

    #pragma unroll
    for (int ni = 0; ni < 2; ++ni) {
        int col = col0 + wn*32 + ni*16 + lr;
        float bre = f32 ? ldin<true>(bor, col) : ldin<false>(bor, col);
        float bim = f32 ? ldin<true>(boi, col) : ldin<false>(boi, col);
        #pragma unroll
        for (int mi = 0; mi < 2; ++mi)
        #pragma unroll
        for (int r = 0; r < 4; ++r) {
            int row = row0 + wm*32 + mi*16 + 4*lg + r;
            float cr = scrub(accr[mi][ni][r] - accs[mi][ni][r] + bre);
            float ci = scrub(acci[mi][ni][r] + bim);
            if (f32) {
                ((float*)out)[(size_t)row*DIM + col]                 = cr;
                ((float*)out)[(size_t)M*DIM + (size_t)row*DIM + col] = ci;
            } else {
                ((bf16*)out)[(size_t)row*DIM + col]                  = __float2bfloat16(cr);
                ((bf16*)out)[(size_t)M*DIM + (size_t)row*DIM + col]  = __float2bfloat16(ci);
            }
        }
    }
}

// ================= host =================
extern "C" void kernel_launch(void* const* d_in, const int* in_sizes, int n_in,
                              void* d_out, int out_size, void* d_ws, size_t ws_size,
                              hipStream_t stream)
{
    const void* xr     = d_in[0];
    const void* xi     = d_in[1];
    const void* fr     = d_in[2];
    const void* fi     = d_in[3];
    const void* Wqkv_r = d_in[4];
    const void* Wqkv_i = d_in[5];
    const void* bqkv_r = d_in[6];
    const void* bqkv_i = d_in[7];
    const void* Wout_r = d_in[8];
    const void* Wout_i = d_in[9];
    const void* bout_r = d_in[10];
    const void* bout_i = d_in[11];

    bf16* w = (bf16*)d_ws;
    const size_t QS  = (size_t)B*HEADS*N*HD;   // 2,097,152
    const size_t XS  = (size_t)M*DIM;          // 2,097,152
    const size_t WQS = (size_t)E3*DIM;         // 3,145,728
    const size_t WOS = (size_t)DIM*DIM;        // 1,048,576

    bf16* qr   = w;          bf16* qi   = qr  + QS;
    bf16* kr   = qi  + QS;   bf16* ki   = kr  + QS;
    bf16* vr   = ki  + QS;   bf16* vi   = vr  + QS;   // TRANSPOSED [b,h,d,n]
    bf16* aor_ = vi  + QS;   bf16* aoi_ = aor_ + QS;
    bf16* xrh = aoi_ + QS;   bf16* xih = xrh + XS;
    bf16* xrl = xih + XS;    bf16* xil = xrl + XS;
    bf16* wqrh = xil + XS;   bf16* wqih = wqrh + WQS;
    bf16* worh = wqih + WQS; bf16* woih = worh + WOS;

    const size_t need = (size_t)(8*QS + 4*XS + 2*WQS + 2*WOS) * sizeof(bf16);
    const bool pre = ws_size >= need;

    if (pre) {
        PrepArgs a;
        a.src[0] = xr;     a.hi[0] = xrh;  a.lo[0] = xrl;    a.n8[0] = (int)(XS/8);
        a.src[1] = xi;     a.hi[1] = xih;  a.lo[1] = xil;    a.n8[1] = (int)(XS/8);
        a.src[2] = Wqkv_r; a.hi[2] = wqrh; a.lo[2] = nullptr; a.n8[2] = (int)(WQS/8);
        a.src[3] = Wqkv_i; a.hi[3] = wqih; a.lo[3] = nullptr; a.n8[3] = (int)(WQS/8);
        a.src[4] = Wout_r; a.hi[4] = worh; a.lo[4] = nullptr; a.n8[4] = (int)(WOS/8);
        a.src[5] = Wout_i; a.hi[5] = woih; a.lo[5] = nullptr; a.n8[5] = (int)(WOS/8);
        prepass_kernel<<<dim3(1536, 6), dim3(256), 0, stream>>>(a);

        qkv_kernel<1><<<dim3((E3/64)*(M/64)), dim3(256), 0, stream>>>(
            xr, xi, fr, fi, Wqkv_r, Wqkv_i, bqkv_r, bqkv_i,
            xrh, xih, xrl, xil, wqrh, wqih,
            qr, qi, kr, ki, vr, vi);
    } else {
        qkv_kernel<2><<<dim3((E3/64)*(M/64)), dim3(256), 0, stream>>>(
            xr, xi, fr, fi, Wqkv_r, Wqkv_i, bqkv_r, bqkv_i,
            nullptr, nullptr, nullptr, nullptr, nullptr, nullptr,
            qr, qi, kr, ki, vr, vi);
    }

    attn_kernel<<<dim3(B*HEADS*(N/64)), dim3(256), 0, stream>>>(
        qr, qi, kr, ki, vr, vi, aor_, aoi_);

    if (pre) {
        outproj_kernel<3><<<dim3((DIM/64)*(M/64)), dim3(256), 0, stream>>>(
            xr, aor_, aoi_, Wout_r, Wout_i, bout_r, bout_i,
            worh, woih, d_out);
    } else {
        outproj_kernel<2><<<dim3((DIM/64)*(M/64)), dim3(256), 0, stream>>>(
            xr, aor_, aoi_, Wout_r, Wout_i, bout_r, bout_i,
            nullptr, nullptr, d_out);
    }
}